// Round 2
// baseline (1172.658 us; speedup 1.0000x reference)
//
#include <hip/hip_runtime.h>
#include <math.h>

// Problem constants (fixed by the reference)
#define BATCH 128
#define FDIM  1536
#define GRP   8192
#define LBL   82
#define HDIM  300
#define TOPK  10
#define CAND  (TOPK * LBL)        // 820

// ---------------- fused fp32 GEMM pair --------------------------------------
// Job A: C1[128,8192] = X[128,1536] @ W0[8192,1536]^T   (+b0 via init kernel)
// Job B: C2[128, 300] = X[128,1536] @ W1[ 300,1536]^T   (+b1 via init kernel)
// Both NT, K-contiguous. One launch; split-K partials via fp32 atomicAdd.
#define BM 128
#define BN 128
#define BK 32
#define LDT 132                 // BM + 4 pad floats (16B-aligned rows)

#define A_SPLIT 6
#define A_KC   (FDIM / A_SPLIT)   // 256  -> 8 iters of BK
#define A_NT   (GRP / BN)         // 64
#define A_BLOCKS (A_NT * A_SPLIT) // 384

#define B_SPLIT 16
#define B_KC   (FDIM / B_SPLIT)   // 96   -> 3 iters of BK
#define B_NT   3                  // ceil(300/128)
#define B_BLOCKS (B_NT * B_SPLIT) // 48

#define TOTAL_BLOCKS (A_BLOCKS + B_BLOCKS) // 432 (<= 2 blocks/CU, all co-resident)

// init: broadcast bias rows into C so split-K blocks can atomicAdd partials.
__global__ __launch_bounds__(256) void init_bias(
    const float* __restrict__ b0, const float* __restrict__ b1,
    float* __restrict__ C1, float* __restrict__ C2)
{
  const int T1 = BATCH * GRP / 4;    // 262144 float4
  const int T2 = BATCH * HDIM / 4;   // 9600 float4
  const int stride = gridDim.x * 256;
  for (int i = blockIdx.x * 256 + threadIdx.x; i < T1; i += stride) {
    const int n4 = i & (GRP / 4 - 1);
    reinterpret_cast<float4*>(C1)[i] = reinterpret_cast<const float4*>(b0)[n4];
  }
  for (int i = blockIdx.x * 256 + threadIdx.x; i < T2; i += stride) {
    const int n4 = i % (HDIM / 4);
    reinterpret_cast<float4*>(C2)[i] = reinterpret_cast<const float4*>(b1)[n4];
  }
}

__global__ __launch_bounds__(256) void gemm_fused(
    const float* __restrict__ A,
    const float* __restrict__ W0, const float* __restrict__ W1,
    float* __restrict__ C1, float* __restrict__ C2)
{
  __shared__ float As[2][BK][LDT];   // transposed: As[k][m]
  __shared__ float Bs[2][BK][LDT];   // transposed: Bs[k][n]

  const int bid = blockIdx.x;
  const float* Bm;
  float* C;
  int N, ldc, n0, kbase, niter;
  if (bid < B_BLOCKS) {              // short job-B blocks first
    const int nt = bid % B_NT, kc = bid / B_NT;
    Bm = W1; C = C2; N = HDIM; ldc = HDIM;
    n0 = nt * BN; kbase = kc * B_KC; niter = B_KC / BK;   // 3
  } else {
    const int q = bid - B_BLOCKS;
    const int nt = q % A_NT, kc = q / A_NT;
    Bm = W0; C = C1; N = GRP; ldc = GRP;
    n0 = nt * BN; kbase = kc * A_KC; niter = A_KC / BK;   // 8
  }

  const int t  = threadIdx.x;
  const int tx = t & 15;             // n-direction (4+4 cols: 4*tx and 64+4*tx)
  const int ty = t >> 4;             // m-direction (8 rows each)
  const int lr = t >> 1;             // staging row 0..127
  const int lk = (t & 1) * 16;       // staging k offset {0,16}

  const float* Arow = A + (size_t)lr * FDIM + kbase + lk;
  int bn = n0 + lr; if (bn > N - 1) bn = N - 1;   // clamp: OOB rows never stored
  const float* Brow = Bm + (size_t)bn * FDIM + kbase + lk;

  float4 ra[4], rb[4];
  float acc[8][8];
#pragma unroll
  for (int i = 0; i < 8; ++i)
#pragma unroll
    for (int j = 0; j < 8; ++j) acc[i][j] = 0.f;

  // prologue load (k-tile 0) + stage to buf 0
#pragma unroll
  for (int i = 0; i < 4; ++i) {
    ra[i] = *reinterpret_cast<const float4*>(Arow + 4 * i);
    rb[i] = *reinterpret_cast<const float4*>(Brow + 4 * i);
  }
#pragma unroll
  for (int i = 0; i < 4; ++i)
#pragma unroll
    for (int c = 0; c < 4; ++c) {
      As[0][lk + 4 * i + c][lr] = reinterpret_cast<const float*>(&ra[i])[c];
      Bs[0][lk + 4 * i + c][lr] = reinterpret_cast<const float*>(&rb[i])[c];
    }
  __syncthreads();

  for (int iter = 0; iter < niter; ++iter) {
    const int buf = iter & 1;
    const bool more = (iter + 1) < niter;
    if (more) {
      const int k0 = (iter + 1) * BK;
#pragma unroll
      for (int i = 0; i < 4; ++i) {
        ra[i] = *reinterpret_cast<const float4*>(Arow + k0 + 4 * i);
        rb[i] = *reinterpret_cast<const float4*>(Brow + k0 + 4 * i);
      }
    }

#pragma unroll
    for (int kk = 0; kk < BK; ++kk) {
      float av[8], bv[8];
      // A: 4 addresses/wave (16-lane broadcast), distinct bank-quads: clean
      *reinterpret_cast<float4*>(&av[0]) = *reinterpret_cast<const float4*>(&As[buf][kk][8 * ty]);
      *reinterpret_cast<float4*>(&av[4]) = *reinterpret_cast<const float4*>(&As[buf][kk][8 * ty + 4]);
      // B: contiguous 16B chunks across tx (stride 16B) -> only free 2-way wrap
      *reinterpret_cast<float4*>(&bv[0]) = *reinterpret_cast<const float4*>(&Bs[buf][kk][4 * tx]);
      *reinterpret_cast<float4*>(&bv[4]) = *reinterpret_cast<const float4*>(&Bs[buf][kk][64 + 4 * tx]);
#pragma unroll
      for (int i = 0; i < 8; ++i)
#pragma unroll
        for (int j = 0; j < 8; ++j)
          acc[i][j] += av[i] * bv[j];
    }

    if (more) {
      const int nb = buf ^ 1;
#pragma unroll
      for (int i = 0; i < 4; ++i)
#pragma unroll
        for (int c = 0; c < 4; ++c) {
          As[nb][lk + 4 * i + c][lr] = reinterpret_cast<const float*>(&ra[i])[c];
          Bs[nb][lk + 4 * i + c][lr] = reinterpret_cast<const float*>(&rb[i])[c];
        }
    }
    __syncthreads();
  }

  // epilogue: atomic split-K accumulate (C pre-initialized with bias)
  // thread's columns: n0 + 4*tx + j (j=0..3) and n0 + 64 + 4*tx + j (j=0..3)
#pragma unroll
  for (int i = 0; i < 8; ++i) {
    const int m = 8 * ty + i;
    float* crow = C + (size_t)m * ldc;
#pragma unroll
    for (int j = 0; j < 4; ++j) {
      const int n = n0 + 4 * tx + j;
      if (n < N) atomicAdd(crow + n, acc[i][j]);
    }
#pragma unroll
    for (int j = 0; j < 4; ++j) {
      const int n = n0 + 64 + 4 * tx + j;
      if (n < N) atomicAdd(crow + n, acc[i][4 + j]);
    }
  }
}

// ---------------- top-k (k=10) per row over 8192 group logits ---------------
// jax.lax.top_k semantics: sorted descending, ties -> lower index.
__global__ __launch_bounds__(256) void topk_kernel(
    const float* __restrict__ logits,      // [128, 8192]
    int*   __restrict__ topk_idx,          // [128, 10]
    float* __restrict__ topk_score)        // [128, 10] (sigmoid of logit)
{
  const int b = blockIdx.x;
  __shared__ unsigned keys[GRP];                 // orderable-encoded logits
  __shared__ unsigned long long red[256];

  {
    const float4* src = reinterpret_cast<const float4*>(logits + (size_t)b * GRP);
    for (int i = threadIdx.x; i < GRP / 4; i += 256) {
      const float4 v = src[i];
      unsigned u;
      u = __float_as_uint(v.x); u ^= (u >> 31) ? 0xFFFFFFFFu : 0x80000000u; keys[4 * i + 0] = u;
      u = __float_as_uint(v.y); u ^= (u >> 31) ? 0xFFFFFFFFu : 0x80000000u; keys[4 * i + 1] = u;
      u = __float_as_uint(v.z); u ^= (u >> 31) ? 0xFFFFFFFFu : 0x80000000u; keys[4 * i + 2] = u;
      u = __float_as_uint(v.w); u ^= (u >> 31) ? 0xFFFFFFFFu : 0x80000000u; keys[4 * i + 3] = u;
    }
  }
  __syncthreads();

  for (int k = 0; k < TOPK; ++k) {
    unsigned long long best = 0ull;
    for (int i = threadIdx.x; i < GRP; i += 256) {
      const unsigned long long key =
          ((unsigned long long)keys[i] << 32) | (unsigned)(GRP - 1 - i);  // ties -> lower i
      if (key > best) best = key;
    }
    red[threadIdx.x] = best;
    __syncthreads();
    if (threadIdx.x < 64) {
      unsigned long long m0 = red[threadIdx.x];
      unsigned long long m1 = red[threadIdx.x + 64];  if (m1 > m0) m0 = m1;
      m1 = red[threadIdx.x + 128]; if (m1 > m0) m0 = m1;
      m1 = red[threadIdx.x + 192]; if (m1 > m0) m0 = m1;
#pragma unroll
      for (int off = 32; off > 0; off >>= 1) {
        const unsigned long long o = __shfl_down(m0, off, 64);
        if (o > m0) m0 = o;
      }
      if (threadIdx.x == 0) {
        const int idx = (GRP - 1) - (int)(m0 & 0xFFFFFFFFu);
        const float lv = logits[(size_t)b * GRP + idx];
        topk_idx[b * TOPK + k]   = idx;
        topk_score[b * TOPK + k] = 1.0f / (1.0f + expf(-lv));
        keys[idx] = 0u;   // remove winner (0 < any finite logit's key)
      }
    }
    __syncthreads();
  }
}

// ---------------- candidate scoring: one wave per (b, candidate) ------------
__global__ __launch_bounds__(256) void score_kernel(
    const int*   __restrict__ group_labels,  // [G*L] (int32 on device)
    const float* __restrict__ embed,         // [N_LABELS, 300]
    const float* __restrict__ emb,           // [128, 300]
    const int*   __restrict__ topk_idx,      // [128, 10]
    const float* __restrict__ topk_score,    // [128, 10]
    float* __restrict__ out_cand,            // [128*820]
    float* __restrict__ out_scores)          // [128*820]
{
  const int wave = (int)((blockIdx.x * 256u + threadIdx.x) >> 6);
  const int lane = threadIdx.x & 63;
  const int total = BATCH * CAND;
  if (wave >= total) return;

  const int b  = wave / CAND;
  const int cc = wave - b * CAND;
  const int k  = cc / LBL;
  const int l  = cc - k * LBL;

  const int g     = topk_idx[b * TOPK + k];
  const int label = group_labels[(size_t)g * LBL + l];

  const float4* er = reinterpret_cast<const float4*>(embed + (size_t)label * HDIM);
  const float4* vv = reinterpret_cast<const float4*>(emb + (size_t)b * HDIM);

  float s = 0.f;
  for (int i = lane; i < HDIM / 4; i += 64) {      // 75 float4 per row
    const float4 e = er[i];
    const float4 x = vv[i];
    s += e.x * x.x + e.y * x.y + e.z * x.z + e.w * x.w;
  }
#pragma unroll
  for (int off = 32; off > 0; off >>= 1) s += __shfl_down(s, off, 64);

  if (lane == 0) {
    const float sc = (1.0f / (1.0f + expf(-s))) * topk_score[b * TOPK + k];
    out_cand[wave]   = (float)label;   // harness reads flat f32; index < 2^24 exact
    out_scores[wave] = sc;
  }
}

extern "C" void kernel_launch(void* const* d_in, const int* in_sizes, int n_in,
                              void* d_out, int out_size, void* d_ws, size_t ws_size,
                              hipStream_t stream) {
  (void)in_sizes; (void)n_in; (void)out_size; (void)ws_size;
  const float* x     = (const float*)d_in[0];   // out  [128,1536]
  const float* W0    = (const float*)d_in[1];   // [8192,1536]
  const float* b0    = (const float*)d_in[2];   // [8192]
  const float* W1    = (const float*)d_in[3];   // [300,1536]
  const float* b1    = (const float*)d_in[4];   // [300]
  const float* embed = (const float*)d_in[5];   // [671744,300]
  const int*   glab  = (const int*)d_in[6];     // [8192*82]
  // d_in[7] = candidates_topk scalar (K=10, hardcoded)

  float* gl       = (float*)d_out;              // [128*8192]
  float* out_cand = gl + BATCH * GRP;           // [128*820]
  float* out_sc   = out_cand + BATCH * CAND;    // [128*820]

  char* ws = (char*)d_ws;
  int*   topk_idx   = (int*)ws;                            // 1280 ints
  float* topk_score = (float*)(ws + 1280 * sizeof(int));   // 1280 floats
  float* emb        = (float*)(ws + 2 * 1280 * 4);         // 128*300 floats

  // K0: broadcast biases into both GEMM outputs (split-K accumulates on top)
  init_bias<<<1024, 256, 0, stream>>>(b0, b1, gl, emb);
  // K1: both GEMMs in one launch; 432 blocks -> 2 blocks/CU co-resident
  gemm_fused<<<TOTAL_BLOCKS, 256, 0, stream>>>(x, W0, W1, gl, emb);
  // K2: top-10 per row
  topk_kernel<<<BATCH, 256, 0, stream>>>(gl, topk_idx, topk_score);
  // K3: candidate expansion + embedding dot + sigmoid*prior
  const int total_waves = BATCH * CAND;                 // 104960
  const int blocks = (total_waves + 3) / 4;             // 4 waves/block
  score_kernel<<<blocks, 256, 0, stream>>>(glab, embed, emb, topk_idx, topk_score,
                                           out_cand, out_sc);
}